// Round 1
// baseline (526.624 us; speedup 1.0000x reference)
//
#include <hip/hip_runtime.h>
#include <hip/hip_bf16.h>
#include <math.h>

// Problem constants
#define BB 4
#define TT 4096
#define DD 1024
#define HH 64
#define MTOT (BB * TT)   // 16384 rows

// ---------------------------------------------------------------------------
// Kernel 1: QKV projection.  C[16384,64] = x[16384,1024] @ W[1024,64]
// blockIdx.y in {0,1,2} selects Wq/Wk/Wv and output slice in workspace.
// Block: 256 threads as 16x16, 64x64 output tile, K staged 16-deep in LDS.
// ---------------------------------------------------------------------------
__global__ __launch_bounds__(256) void qkv_proj(
    const float* __restrict__ x,
    const float* __restrict__ Wq,
    const float* __restrict__ Wk,
    const float* __restrict__ Wv,
    float* __restrict__ qkv)
{
    const int tid = threadIdx.x;
    const int tx = tid & 15;        // output col group (4 cols)
    const int ty = tid >> 4;        // output row group (4 rows)
    const int m0 = blockIdx.x * 64; // row tile base
    const int w  = blockIdx.y;

    const float* W = (w == 0) ? Wq : (w == 1) ? Wk : Wv;
    float* out = qkv + (size_t)w * MTOT * HH;

    __shared__ float As[16][64];  // [k][m]  (transposed x tile)
    __shared__ float Bs[16][64];  // [k][n]

    // loader indices
    const int arow = tid >> 2;    // 0..63 row of A tile
    const int ak4  = tid & 3;     // which float4 along k (16 k = 4 float4)
    const int brow = tid >> 4;    // 0..15 k-row of B tile
    const int bn4  = tid & 15;    // float4 along n

    float acc[4][4];
#pragma unroll
    for (int i = 0; i < 4; ++i)
#pragma unroll
        for (int j = 0; j < 4; ++j) acc[i][j] = 0.0f;

    for (int kc = 0; kc < DD; kc += 16) {
        __syncthreads();
        float4 av = *(const float4*)&x[(size_t)(m0 + arow) * DD + kc + ak4 * 4];
        As[ak4 * 4 + 0][arow] = av.x;
        As[ak4 * 4 + 1][arow] = av.y;
        As[ak4 * 4 + 2][arow] = av.z;
        As[ak4 * 4 + 3][arow] = av.w;
        float4 bv = *(const float4*)&W[(size_t)(kc + brow) * HH + bn4 * 4];
        *(float4*)&Bs[brow][bn4 * 4] = bv;
        __syncthreads();

#pragma unroll
        for (int kk = 0; kk < 16; ++kk) {
            float4 a = *(float4*)&As[kk][ty * 4];
            float4 b = *(float4*)&Bs[kk][tx * 4];
            float af[4] = {a.x, a.y, a.z, a.w};
            float bf[4] = {b.x, b.y, b.z, b.w};
#pragma unroll
            for (int i = 0; i < 4; ++i)
#pragma unroll
                for (int j = 0; j < 4; ++j)
                    acc[i][j] = fmaf(af[i], bf[j], acc[i][j]);
        }
    }

#pragma unroll
    for (int r = 0; r < 4; ++r) {
        float4 o = {acc[r][0], acc[r][1], acc[r][2], acc[r][3]};
        *(float4*)&out[(size_t)(m0 + ty * 4 + r) * HH + tx * 4] = o;
    }
}

// ---------------------------------------------------------------------------
// Kernel 2: causal flash attention, one head, head dim 64.
// Grid: (T/64, B).  Block: 256 threads as 16x16; thread owns 4 rows x 4 cols.
// Online softmax, P round-trips through LDS for the PV GEMM.
// ---------------------------------------------------------------------------
__global__ __launch_bounds__(256) void flash_attn(
    const float* __restrict__ qkv,
    float* __restrict__ out)
{
    const int qt  = blockIdx.x;   // q tile index, 0..63
    const int b   = blockIdx.y;   // batch
    const int tid = threadIdx.x;
    const int tx  = tid & 15;
    const int ty  = tid >> 4;

    const float* q_g = qkv + (size_t)b * TT * HH;
    const float* k_g = qkv + (size_t)MTOT * HH + (size_t)b * TT * HH;
    const float* v_g = qkv + (size_t)2 * MTOT * HH + (size_t)b * TT * HH;

    __shared__ float Qs[64][68];  // [h][r] transposed
    __shared__ float Ks[64][68];  // [h][c] transposed
    __shared__ float Vs[64][68];  // [c][h] natural
    __shared__ float Ps[64][68];  // [c][r] transposed

    // Load Q tile transposed: 4096 floats = 1024 float4, 4 per thread.
#pragma unroll
    for (int i = 0; i < 4; ++i) {
        int f  = tid + i * 256;
        int r  = f >> 4;        // 0..63
        int h4 = f & 15;        // float4 along h
        float4 v = *(const float4*)&q_g[(size_t)(qt * 64 + r) * HH + h4 * 4];
        Qs[h4 * 4 + 0][r] = v.x;
        Qs[h4 * 4 + 1][r] = v.y;
        Qs[h4 * 4 + 2][r] = v.z;
        Qs[h4 * 4 + 3][r] = v.w;
    }

    float m_i[4], l_i[4], acc[4][4];
#pragma unroll
    for (int r = 0; r < 4; ++r) {
        m_i[r] = -1e30f;
        l_i[r] = 0.0f;
#pragma unroll
        for (int c = 0; c < 4; ++c) acc[r][c] = 0.0f;
    }

    for (int j = 0; j <= qt; ++j) {
        __syncthreads();  // previous iter done with Ks/Vs (and its Ps reads)
        // Load K tile (transposed) and V tile (natural)
#pragma unroll
        for (int i = 0; i < 4; ++i) {
            int f  = tid + i * 256;
            int r  = f >> 4;
            int h4 = f & 15;
            float4 kv = *(const float4*)&k_g[(size_t)(j * 64 + r) * HH + h4 * 4];
            Ks[h4 * 4 + 0][r] = kv.x;
            Ks[h4 * 4 + 1][r] = kv.y;
            Ks[h4 * 4 + 2][r] = kv.z;
            Ks[h4 * 4 + 3][r] = kv.w;
            float4 vv = *(const float4*)&v_g[(size_t)(j * 64 + r) * HH + h4 * 4];
            *(float4*)&Vs[r][h4 * 4] = vv;
        }
        __syncthreads();

        // S = Q K^T * 0.125
        float s[4][4];
#pragma unroll
        for (int r = 0; r < 4; ++r)
#pragma unroll
            for (int c = 0; c < 4; ++c) s[r][c] = 0.0f;

#pragma unroll 8
        for (int h = 0; h < 64; ++h) {
            float4 a = *(float4*)&Qs[h][ty * 4];
            float4 bb = *(float4*)&Ks[h][tx * 4];
            float af[4] = {a.x, a.y, a.z, a.w};
            float bf[4] = {bb.x, bb.y, bb.z, bb.w};
#pragma unroll
            for (int r = 0; r < 4; ++r)
#pragma unroll
                for (int c = 0; c < 4; ++c)
                    s[r][c] = fmaf(af[r], bf[c], s[r][c]);
        }

#pragma unroll
        for (int r = 0; r < 4; ++r)
#pragma unroll
            for (int c = 0; c < 4; ++c) s[r][c] *= 0.125f;

        // Causal mask (only the diagonal tile has masked entries)
        if (j == qt) {
#pragma unroll
            for (int r = 0; r < 4; ++r)
#pragma unroll
                for (int c = 0; c < 4; ++c)
                    if (tx * 4 + c > ty * 4 + r) s[r][c] = -1e30f;
        }

        // Online softmax: row max across the 16 tx lanes of each row
        float m_new[4], alpha[4];
#pragma unroll
        for (int r = 0; r < 4; ++r) {
            float mt = fmaxf(fmaxf(s[r][0], s[r][1]), fmaxf(s[r][2], s[r][3]));
#pragma unroll
            for (int off = 1; off < 16; off <<= 1)
                mt = fmaxf(mt, __shfl_xor(mt, off));
            m_new[r] = fmaxf(m_i[r], mt);
            alpha[r] = __expf(m_i[r] - m_new[r]);
            m_i[r]   = m_new[r];
        }

        // p = exp(s - m_new), row sums, write P transposed to LDS
        float rs[4];
#pragma unroll
        for (int r = 0; r < 4; ++r) {
            float sum = 0.0f;
#pragma unroll
            for (int c = 0; c < 4; ++c) {
                float p = __expf(s[r][c] - m_new[r]);
                s[r][c] = p;   // reuse s as p
                sum += p;
            }
#pragma unroll
            for (int off = 1; off < 16; off <<= 1)
                sum += __shfl_xor(sum, off);
            rs[r] = sum;
            l_i[r] = l_i[r] * alpha[r] + sum;
        }

#pragma unroll
        for (int r = 0; r < 4; ++r)
#pragma unroll
            for (int c = 0; c < 4; ++c)
                Ps[tx * 4 + c][ty * 4 + r] = s[r][c];

        // rescale accumulator
#pragma unroll
        for (int r = 0; r < 4; ++r)
#pragma unroll
            for (int c = 0; c < 4; ++c) acc[r][c] *= alpha[r];

        __syncthreads();

        // O += P V  :  O[r][h] += sum_c P[r][c] * V[c][h]
#pragma unroll 8
        for (int c = 0; c < 64; ++c) {
            float4 pv = *(float4*)&Ps[c][ty * 4];
            float4 vv = *(float4*)&Vs[c][tx * 4];
            float pf[4] = {pv.x, pv.y, pv.z, pv.w};
            float vf[4] = {vv.x, vv.y, vv.z, vv.w};
#pragma unroll
            for (int r = 0; r < 4; ++r)
#pragma unroll
                for (int h = 0; h < 4; ++h)
                    acc[r][h] = fmaf(pf[r], vf[h], acc[r][h]);
        }
    }

    // Epilogue: normalize and store
#pragma unroll
    for (int r = 0; r < 4; ++r) {
        float inv = 1.0f / l_i[r];
        float4 o = {acc[r][0] * inv, acc[r][1] * inv, acc[r][2] * inv, acc[r][3] * inv};
        *(float4*)&out[((size_t)b * TT + qt * 64 + ty * 4 + r) * HH + tx * 4] = o;
    }
}

extern "C" void kernel_launch(void* const* d_in, const int* in_sizes, int n_in,
                              void* d_out, int out_size, void* d_ws, size_t ws_size,
                              hipStream_t stream) {
    const float* x  = (const float*)d_in[0];
    const float* Wq = (const float*)d_in[1];
    const float* Wk = (const float*)d_in[2];
    const float* Wv = (const float*)d_in[3];
    float* out = (float*)d_out;
    float* qkv = (float*)d_ws;   // 3 * 16384 * 64 floats = 12.6 MB

    qkv_proj<<<dim3(MTOT / 64, 3), 256, 0, stream>>>(x, Wq, Wk, Wv, qkv);
    flash_attn<<<dim3(TT / 64, BB), 256, 0, stream>>>(qkv, out);
}

// Round 2
// 262.277 us; speedup vs baseline: 2.0079x; 2.0079x over previous
//
#include <hip/hip_runtime.h>
#include <hip/hip_bf16.h>
#include <math.h>

#define BB 4
#define TT 4096
#define DD 1024
#define HH 64
#define MTOT (BB * TT)   // 16384 rows
#define LD 72            // padded LDS row stride (shorts): 144 B, 16B-aligned

typedef short short8 __attribute__((ext_vector_type(8)));
typedef float f32x4  __attribute__((ext_vector_type(4)));

__device__ inline unsigned short f2bf(float f) {
    unsigned u = __builtin_bit_cast(unsigned, f);
    unsigned r = (u + 0x7fffu + ((u >> 16) & 1u)) >> 16;
    return (unsigned short)r;
}

__device__ inline unsigned long long pack4(float a, float b, float c, float d) {
    return (unsigned long long)f2bf(a) |
           ((unsigned long long)f2bf(b) << 16) |
           ((unsigned long long)f2bf(c) << 32) |
           ((unsigned long long)f2bf(d) << 48);
}

__device__ inline short8 pack8(float4 a, float4 b) {
    short8 r;
    r[0] = (short)f2bf(a.x); r[1] = (short)f2bf(a.y);
    r[2] = (short)f2bf(a.z); r[3] = (short)f2bf(a.w);
    r[4] = (short)f2bf(b.x); r[5] = (short)f2bf(b.y);
    r[6] = (short)f2bf(b.z); r[7] = (short)f2bf(b.w);
    return r;
}

// ---------------------------------------------------------------------------
// Kernel 0: transpose W (1024x64 fp32) -> Wt (64x1024 bf16), 3 matrices.
// Wt lives in d_out (384 KB), which flash_attn fully overwrites afterwards.
// ---------------------------------------------------------------------------
__global__ __launch_bounds__(256) void transpose_w(
    const float* __restrict__ Wq, const float* __restrict__ Wk,
    const float* __restrict__ Wv, unsigned short* __restrict__ Wt)
{
    const int w = blockIdx.y;
    const float* W = (w == 0) ? Wq : (w == 1) ? Wk : Wv;
    unsigned short* o = Wt + (size_t)w * 64 * 1024;
    const int t  = threadIdx.x;
    const int n4 = t & 15;
    const int k0 = blockIdx.x * 64 + (t >> 4) * 4;

    float v[4][4];
#pragma unroll
    for (int ii = 0; ii < 4; ++ii) {
        float4 r = *(const float4*)&W[(size_t)(k0 + ii) * HH + n4 * 4];
        v[ii][0] = r.x; v[ii][1] = r.y; v[ii][2] = r.z; v[ii][3] = r.w;
    }
#pragma unroll
    for (int cc = 0; cc < 4; ++cc) {
        unsigned long long pk = pack4(v[0][cc], v[1][cc], v[2][cc], v[3][cc]);
        *(unsigned long long*)&o[(size_t)(n4 * 4 + cc) * 1024 + k0] = pk;
    }
}

// ---------------------------------------------------------------------------
// Kernel 1: QKV projection via MFMA.  qkv[w][16384,64] = x @ W_w, bf16 inputs.
// Grid (256, 3), 4 waves/block; wave owns a 16-row strip of a 64-row tile.
// A-frags straight from global x (fp32->bf16), B-frags from L2-resident Wt.
// No LDS, no barriers.
// ---------------------------------------------------------------------------
__global__ __launch_bounds__(256) void qkv_proj(
    const float* __restrict__ x,
    const unsigned short* __restrict__ Wt,
    float* __restrict__ qkv)
{
    const int tid  = threadIdx.x;
    const int lane = tid & 63;
    const int wave = tid >> 6;
    const int l15  = lane & 15;
    const int quad = lane >> 4;
    const int m0   = blockIdx.x * 64;
    const int w    = blockIdx.y;

    const unsigned short* Wp = Wt + (size_t)w * 64 * 1024;
    const float* xr = x + (size_t)(m0 + wave * 16 + l15) * DD + quad * 8;

    f32x4 acc[4];
#pragma unroll
    for (int i = 0; i < 4; ++i) acc[i] = (f32x4){0.f, 0.f, 0.f, 0.f};

#pragma unroll 4
    for (int k0 = 0; k0 < DD; k0 += 32) {
        float4 a0 = *(const float4*)(xr + k0);
        float4 a1 = *(const float4*)(xr + k0 + 4);
        short8 af = pack8(a0, a1);
#pragma unroll
        for (int nt = 0; nt < 4; ++nt) {
            short8 bf = *(const short8*)&Wp[(size_t)(nt * 16 + l15) * 1024 + k0 + quad * 8];
            acc[nt] = __builtin_amdgcn_mfma_f32_16x16x32_bf16(af, bf, acc[nt], 0, 0, 0);
        }
    }

    float* outp = qkv + (size_t)w * MTOT * HH;
#pragma unroll
    for (int nt = 0; nt < 4; ++nt)
#pragma unroll
        for (int r = 0; r < 4; ++r)
            outp[(size_t)(m0 + wave * 16 + quad * 4 + r) * HH + nt * 16 + l15] = acc[nt][r];
}

// ---------------------------------------------------------------------------
// Kernel 2: causal flash attention with MFMA.
// Grid (64, 4), 4 waves/block; wave owns 16 q rows of a 64-row q tile.
// Computes S^T = K·Q^T (Q frags double as B-operand), softmax across quads,
// P -> per-wave LDS strip in A-operand order (packed b64), O += P·V from
// LDS-transposed V.  Two barriers per key tile (K/V staging only).
// ---------------------------------------------------------------------------
__global__ __launch_bounds__(256) void flash_attn(
    const float* __restrict__ qkv,
    float* __restrict__ out)
{
    const int qt   = blockIdx.x;
    const int b    = blockIdx.y;
    const int tid  = threadIdx.x;
    const int lane = tid & 63;
    const int wave = tid >> 6;
    const int l15  = lane & 15;
    const int quad = lane >> 4;

    const float* q_g = qkv + (size_t)b * TT * HH;
    const float* k_g = qkv + (size_t)(MTOT + b * TT) * HH;
    const float* v_g = qkv + (size_t)(2 * MTOT + b * TT) * HH;

    __shared__ unsigned short Ks[64 * LD];      // [key][h]  bf16
    __shared__ unsigned short Vt[64 * LD];      // [h][key]  bf16 (transposed)
    __shared__ unsigned short Ps[4 * 16 * LD];  // per-wave [q][key] bf16
    unsigned short* Pw = Ps + wave * 16 * LD;

    // Q fragments (registers, reused every tile; also serve as B-operand)
    short8 qf[2];
    {
        const float* qp = q_g + (size_t)(qt * 64 + wave * 16 + l15) * HH + quad * 8;
#pragma unroll
        for (int kk = 0; kk < 2; ++kk) {
            float4 a0 = *(const float4*)(qp + kk * 32);
            float4 a1 = *(const float4*)(qp + kk * 32 + 4);
            qf[kk] = pack8(a0, a1);
        }
    }

    f32x4 ov[4];
#pragma unroll
    for (int i = 0; i < 4; ++i) ov[i] = (f32x4){0.f, 0.f, 0.f, 0.f};
    float m_run = -1e30f, l_run = 0.f;

    for (int j = 0; j <= qt; ++j) {
        __syncthreads();   // all waves done reading previous Ks/Vt

        // ---- stage K tile: [key][h] bf16, packed b64 writes
#pragma unroll
        for (int i = 0; i < 4; ++i) {
            int f = tid + i * 256;
            int row = f >> 4, h4 = f & 15;
            float4 kv = *(const float4*)(k_g + (size_t)(j * 64 + row) * HH + h4 * 4);
            *(unsigned long long*)&Ks[row * LD + h4 * 4] = pack4(kv.x, kv.y, kv.z, kv.w);
        }
        // ---- stage V tile transposed: Vt[h][key]
        {
            int n4 = tid & 15, k0 = (tid >> 4) * 4;
            float vv[4][4];
#pragma unroll
            for (int ii = 0; ii < 4; ++ii) {
                float4 r = *(const float4*)(v_g + (size_t)(j * 64 + k0 + ii) * HH + n4 * 4);
                vv[ii][0] = r.x; vv[ii][1] = r.y; vv[ii][2] = r.z; vv[ii][3] = r.w;
            }
#pragma unroll
            for (int cc = 0; cc < 4; ++cc) {
                *(unsigned long long*)&Vt[(n4 * 4 + cc) * LD + k0] =
                    pack4(vv[0][cc], vv[1][cc], vv[2][cc], vv[3][cc]);
            }
        }
        __syncthreads();

        // ---- S^T = K · Q^T  (per wave: 64 keys x 16 q)
        f32x4 st[4];
#pragma unroll
        for (int i = 0; i < 4; ++i) st[i] = (f32x4){0.f, 0.f, 0.f, 0.f};
#pragma unroll
        for (int kk = 0; kk < 2; ++kk)
#pragma unroll
            for (int mt = 0; mt < 4; ++mt) {
                short8 a = *(const short8*)&Ks[(mt * 16 + l15) * LD + kk * 32 + quad * 8];
                st[mt] = __builtin_amdgcn_mfma_f32_16x16x32_bf16(a, qf[kk], st[mt], 0, 0, 0);
            }

        // ---- scale + causal mask (lane holds key = mt*16+quad*4+r, q = l15)
#pragma unroll
        for (int mt = 0; mt < 4; ++mt)
#pragma unroll
            for (int r = 0; r < 4; ++r) st[mt][r] *= 0.125f;
        if (j == qt) {
            int qg = wave * 16 + l15;
#pragma unroll
            for (int mt = 0; mt < 4; ++mt)
#pragma unroll
                for (int r = 0; r < 4; ++r)
                    if (mt * 16 + quad * 4 + r > qg) st[mt][r] = -1e30f;
        }

        // ---- online softmax (per q = l15; reduce across quads)
        float mloc = -1e30f;
#pragma unroll
        for (int mt = 0; mt < 4; ++mt)
#pragma unroll
            for (int r = 0; r < 4; ++r) mloc = fmaxf(mloc, st[mt][r]);
        mloc = fmaxf(mloc, __shfl_xor(mloc, 16));
        mloc = fmaxf(mloc, __shfl_xor(mloc, 32));
        float m_new = fmaxf(m_run, mloc);
        float alpha = __expf(m_run - m_new);
        m_run = m_new;

        float ssum = 0.f;
#pragma unroll
        for (int mt = 0; mt < 4; ++mt)
#pragma unroll
            for (int r = 0; r < 4; ++r) {
                float p = __expf(st[mt][r] - m_new);
                st[mt][r] = p;
                ssum += p;
            }
        ssum += __shfl_xor(ssum, 16);
        ssum += __shfl_xor(ssum, 32);
        l_run = l_run * alpha + ssum;

        // ---- write P to per-wave LDS strip in A-operand order (no barrier)
#pragma unroll
        for (int mt = 0; mt < 4; ++mt)
            *(unsigned long long*)&Pw[l15 * LD + mt * 16 + quad * 4] =
                pack4(st[mt][0], st[mt][1], st[mt][2], st[mt][3]);

        // ---- rescale O (O frag row q = quad*4+r; alpha lives at lane q)
        float a4[4];
#pragma unroll
        for (int r = 0; r < 4; ++r) a4[r] = __shfl(alpha, quad * 4 + r);
#pragma unroll
        for (int ht = 0; ht < 4; ++ht)
#pragma unroll
            for (int r = 0; r < 4; ++r) ov[ht][r] *= a4[r];

        // ---- O += P · V
#pragma unroll
        for (int kk = 0; kk < 2; ++kk) {
            short8 a = *(const short8*)&Pw[l15 * LD + kk * 32 + quad * 8];
#pragma unroll
            for (int ht = 0; ht < 4; ++ht) {
                short8 bf = *(const short8*)&Vt[(ht * 16 + l15) * LD + kk * 32 + quad * 8];
                ov[ht] = __builtin_amdgcn_mfma_f32_16x16x32_bf16(a, bf, ov[ht], 0, 0, 0);
            }
        }
    }

    // ---- epilogue: normalize, store
    float l4[4];
#pragma unroll
    for (int r = 0; r < 4; ++r) l4[r] = __shfl(l_run, quad * 4 + r);
#pragma unroll
    for (int ht = 0; ht < 4; ++ht)
#pragma unroll
        for (int r = 0; r < 4; ++r) {
            float val = ov[ht][r] / l4[r];
            out[((size_t)b * TT + qt * 64 + wave * 16 + quad * 4 + r) * HH + ht * 16 + l15] = val;
        }
}

extern "C" void kernel_launch(void* const* d_in, const int* in_sizes, int n_in,
                              void* d_out, int out_size, void* d_ws, size_t ws_size,
                              hipStream_t stream) {
    const float* x  = (const float*)d_in[0];
    const float* Wq = (const float*)d_in[1];
    const float* Wk = (const float*)d_in[2];
    const float* Wv = (const float*)d_in[3];
    float* out = (float*)d_out;
    float* qkv = (float*)d_ws;                       // 12.58 MB
    unsigned short* Wt = (unsigned short*)d_out;     // 384 KB pre-scratch, fully
                                                     // overwritten by flash_attn

    transpose_w<<<dim3(16, 3), 256, 0, stream>>>(Wq, Wk, Wv, Wt);
    qkv_proj<<<dim3(MTOT / 64, 3), 256, 0, stream>>>(x, Wt, qkv);
    flash_attn<<<dim3(TT / 64, BB), 256, 0, stream>>>(qkv, out);
}

// Round 3
// 200.968 us; speedup vs baseline: 2.6204x; 1.3051x over previous
//
#include <hip/hip_runtime.h>
#include <hip/hip_bf16.h>
#include <math.h>

#define BB 4
#define TT 4096
#define DD 1024
#define HH 64
#define MTOT (BB * TT)   // 16384 rows
#define LD 72            // padded LDS row stride (shorts)
#define NCH 4            // key chunks per q row-block (1024 keys each)

typedef short short8 __attribute__((ext_vector_type(8)));
typedef float f32x4  __attribute__((ext_vector_type(4)));

__device__ inline unsigned short f2bf(float f) {
    unsigned u = __builtin_bit_cast(unsigned, f);
    unsigned r = (u + 0x7fffu + ((u >> 16) & 1u)) >> 16;
    return (unsigned short)r;
}

__device__ inline unsigned long long pack4(float a, float b, float c, float d) {
    return (unsigned long long)f2bf(a) |
           ((unsigned long long)f2bf(b) << 16) |
           ((unsigned long long)f2bf(c) << 32) |
           ((unsigned long long)f2bf(d) << 48);
}

__device__ inline short8 pack8(float4 a, float4 b) {
    short8 r;
    r[0] = (short)f2bf(a.x); r[1] = (short)f2bf(a.y);
    r[2] = (short)f2bf(a.z); r[3] = (short)f2bf(a.w);
    r[4] = (short)f2bf(b.x); r[5] = (short)f2bf(b.y);
    r[6] = (short)f2bf(b.z); r[7] = (short)f2bf(b.w);
    return r;
}

// Workspace layout (element offsets):
//   q_bf : ushort[1M]   [b][t][h]
//   k_bf : ushort[1M]   [b][t][h]
//   vt_bf: ushort[1M]   [b][h][t]   (pre-transposed V)
//   Opart: float[4M]    [b][qt][c][row64][h64]  (unnormalized partial O)
//   Mpart: float[64K]   [b][qt][c][row64]
//   Lpart: float[64K]   [b][qt][c][row64]
#define QOFF  0
#define KOFF  (MTOT * HH)
#define VOFF  (2 * MTOT * HH)
#define BF_TOTAL (3 * MTOT * HH)

// ---------------------------------------------------------------------------
// Kernel 0: transpose W (1024x64 fp32) -> Wt (64x1024 bf16), 3 matrices.
// Wt lives in d_out (384 KB), fully overwritten by combine afterwards.
// ---------------------------------------------------------------------------
__global__ __launch_bounds__(256) void transpose_w(
    const float* __restrict__ Wq, const float* __restrict__ Wk,
    const float* __restrict__ Wv, unsigned short* __restrict__ Wt)
{
    const int w = blockIdx.y;
    const float* W = (w == 0) ? Wq : (w == 1) ? Wk : Wv;
    unsigned short* o = Wt + (size_t)w * 64 * 1024;
    const int t  = threadIdx.x;
    const int n4 = t & 15;
    const int k0 = blockIdx.x * 64 + (t >> 4) * 4;

    float v[4][4];
#pragma unroll
    for (int ii = 0; ii < 4; ++ii) {
        float4 r = *(const float4*)&W[(size_t)(k0 + ii) * HH + n4 * 4];
        v[ii][0] = r.x; v[ii][1] = r.y; v[ii][2] = r.z; v[ii][3] = r.w;
    }
#pragma unroll
    for (int cc = 0; cc < 4; ++cc) {
        unsigned long long pk = pack4(v[0][cc], v[1][cc], v[2][cc], v[3][cc]);
        *(unsigned long long*)&o[(size_t)(n4 * 4 + cc) * 1024 + k0] = pk;
    }
}

// ---------------------------------------------------------------------------
// Kernel 1: fused QKV projection.  Reads x ONCE, produces q/k bf16 [b][t][h]
// and v bf16 pre-transposed [b][h][t].
// Grid 512 blocks x 256 thr.  Block = 32 rows; 4 waves = 2 row-strips x
// 2 K-halves (k-split doubles waves/SIMD); LDS combine of partials.
// ---------------------------------------------------------------------------
__global__ __launch_bounds__(256) void qkv_proj(
    const float* __restrict__ x,
    const unsigned short* __restrict__ Wt,
    unsigned short* __restrict__ qkv)
{
    const int tid  = threadIdx.x;
    const int lane = tid & 63;
    const int wave = tid >> 6;
    const int l15  = lane & 15;
    const int quad = lane >> 4;
    const int s    = wave & 1;    // row strip
    const int kh   = wave >> 1;   // k half
    const int m0   = blockIdx.x * 32;

    __shared__ f32x4 comb[2][64][12];

    const float* xr = x + (size_t)(m0 + s * 16 + l15) * DD + kh * 512 + quad * 8;

    f32x4 acc[3][4];
#pragma unroll
    for (int w = 0; w < 3; ++w)
#pragma unroll
        for (int i = 0; i < 4; ++i) acc[w][i] = (f32x4){0.f, 0.f, 0.f, 0.f};

#pragma unroll 4
    for (int k0 = 0; k0 < 512; k0 += 32) {
        float4 a0 = *(const float4*)(xr + k0);
        float4 a1 = *(const float4*)(xr + k0 + 4);
        short8 af = pack8(a0, a1);
#pragma unroll
        for (int w = 0; w < 3; ++w)
#pragma unroll
            for (int nt = 0; nt < 4; ++nt) {
                short8 bf = *(const short8*)&Wt[(size_t)w * 65536 +
                    (size_t)(nt * 16 + l15) * 1024 + kh * 512 + k0 + quad * 8];
                acc[w][nt] = __builtin_amdgcn_mfma_f32_16x16x32_bf16(af, bf, acc[w][nt], 0, 0, 0);
            }
    }

    if (kh == 1) {
#pragma unroll
        for (int w = 0; w < 3; ++w)
#pragma unroll
            for (int nt = 0; nt < 4; ++nt) comb[s][lane][w * 4 + nt] = acc[w][nt];
    }
    __syncthreads();
    if (kh == 1) return;

#pragma unroll
    for (int w = 0; w < 3; ++w)
#pragma unroll
        for (int nt = 0; nt < 4; ++nt) acc[w][nt] += comb[s][lane][w * 4 + nt];

    unsigned short* q_bf  = qkv + QOFF;
    unsigned short* k_bf  = qkv + KOFF;
    unsigned short* vt_bf = qkv + VOFF;
#pragma unroll
    for (int nt = 0; nt < 4; ++nt) {
        int col = nt * 16 + l15;
#pragma unroll
        for (int r = 0; r < 4; ++r) {
            int m = m0 + s * 16 + quad * 4 + r;   // global row = b*T + t
            q_bf[(size_t)m * HH + col] = f2bf(acc[0][nt][r]);
            k_bf[(size_t)m * HH + col] = f2bf(acc[1][nt][r]);
            int b = m >> 12, t = m & 4095;
            vt_bf[(size_t)b * HH * TT + (size_t)col * TT + t] = f2bf(acc[2][nt][r]);
        }
    }
}

// ---------------------------------------------------------------------------
// Kernel 2: causal flash attention, key-split.  Grid (qt=64, b=4, chunk=4).
// Chunk c covers keys [c*1024, min(c*1024+1024, (qt+1)*64)).  Blocks with
// c*16 > qt exit.  Writes unnormalized partial O + (m,l) per row to ws.
// ---------------------------------------------------------------------------
__global__ __launch_bounds__(256) void flash_attn(
    const unsigned short* __restrict__ qkv,
    float* __restrict__ Opart,
    float* __restrict__ Mpart,
    float* __restrict__ Lpart)
{
    const int qt = blockIdx.x;
    const int b  = blockIdx.y;
    const int c  = blockIdx.z;
    if (c * 16 > qt) return;
    const int j0   = c * 16;
    const int jmax = min(j0 + 16, qt + 1);

    const int tid  = threadIdx.x;
    const int lane = tid & 63;
    const int wave = tid >> 6;
    const int l15  = lane & 15;
    const int quad = lane >> 4;

    const unsigned short* q_g  = qkv + QOFF + (size_t)b * TT * HH;
    const unsigned short* k_g  = qkv + KOFF + (size_t)b * TT * HH;
    const unsigned short* vt_g = qkv + VOFF + (size_t)b * HH * TT;

    __shared__ unsigned short Ks[64 * LD];      // [key][h]
    __shared__ unsigned short Vs[64 * LD];      // [h][key]
    __shared__ unsigned short Ps[4 * 16 * LD];  // per-wave [q][key]
    unsigned short* Pw = Ps + wave * 16 * LD;

    // Q fragments (bf16 direct)
    short8 qf[2];
#pragma unroll
    for (int kk = 0; kk < 2; ++kk)
        qf[kk] = *(const short8*)&q_g[(size_t)(qt * 64 + wave * 16 + l15) * HH + kk * 32 + quad * 8];

    f32x4 ov[4];
#pragma unroll
    for (int i = 0; i < 4; ++i) ov[i] = (f32x4){0.f, 0.f, 0.f, 0.f};
    float m_run = -1e30f, l_run = 0.f;

    const int srow = tid >> 3;   // 0..31
    const int seg  = tid & 7;    // 16B segment within a 128B row

    for (int j = j0; j < jmax; ++j) {
        __syncthreads();
        // stage K [key][h] and V^T [h][key]: 8 KB each, 16B copies
#pragma unroll
        for (int r2 = 0; r2 < 2; ++r2) {
            int row = srow + r2 * 32;
            *(ulonglong2*)&Ks[row * LD + seg * 8] =
                *(const ulonglong2*)&k_g[(size_t)(j * 64 + row) * HH + seg * 8];
            *(ulonglong2*)&Vs[row * LD + seg * 8] =
                *(const ulonglong2*)&vt_g[(size_t)row * TT + j * 64 + seg * 8];
        }
        __syncthreads();

        // S^T = K · Q^T  (wave: 64 keys x 16 q)
        f32x4 st[4];
#pragma unroll
        for (int i = 0; i < 4; ++i) st[i] = (f32x4){0.f, 0.f, 0.f, 0.f};
#pragma unroll
        for (int kk = 0; kk < 2; ++kk)
#pragma unroll
            for (int mt = 0; mt < 4; ++mt) {
                short8 a = *(const short8*)&Ks[(mt * 16 + l15) * LD + kk * 32 + quad * 8];
                st[mt] = __builtin_amdgcn_mfma_f32_16x16x32_bf16(a, qf[kk], st[mt], 0, 0, 0);
            }

#pragma unroll
        for (int mt = 0; mt < 4; ++mt)
#pragma unroll
            for (int r = 0; r < 4; ++r) st[mt][r] *= 0.125f;
        if (j == qt) {
            int qg = wave * 16 + l15;
#pragma unroll
            for (int mt = 0; mt < 4; ++mt)
#pragma unroll
                for (int r = 0; r < 4; ++r)
                    if (mt * 16 + quad * 4 + r > qg) st[mt][r] = -1e30f;
        }

        // online softmax for q = l15 (reduce across quads)
        float mloc = -1e30f;
#pragma unroll
        for (int mt = 0; mt < 4; ++mt)
#pragma unroll
            for (int r = 0; r < 4; ++r) mloc = fmaxf(mloc, st[mt][r]);
        mloc = fmaxf(mloc, __shfl_xor(mloc, 16));
        mloc = fmaxf(mloc, __shfl_xor(mloc, 32));
        float m_new = fmaxf(m_run, mloc);
        float alpha = __expf(m_run - m_new);
        m_run = m_new;

        float ssum = 0.f;
#pragma unroll
        for (int mt = 0; mt < 4; ++mt)
#pragma unroll
            for (int r = 0; r < 4; ++r) {
                float p = __expf(st[mt][r] - m_new);
                st[mt][r] = p;
                ssum += p;
            }
        ssum += __shfl_xor(ssum, 16);
        ssum += __shfl_xor(ssum, 32);
        l_run = l_run * alpha + ssum;

        // P -> per-wave LDS strip in A-operand order
#pragma unroll
        for (int mt = 0; mt < 4; ++mt)
            *(unsigned long long*)&Pw[l15 * LD + mt * 16 + quad * 4] =
                pack4(st[mt][0], st[mt][1], st[mt][2], st[mt][3]);

        // rescale O
        float a4[4];
#pragma unroll
        for (int r = 0; r < 4; ++r) a4[r] = __shfl(alpha, quad * 4 + r);
#pragma unroll
        for (int ht = 0; ht < 4; ++ht)
#pragma unroll
            for (int r = 0; r < 4; ++r) ov[ht][r] *= a4[r];

        // O += P · V
#pragma unroll
        for (int kk = 0; kk < 2; ++kk) {
            short8 a = *(const short8*)&Pw[l15 * LD + kk * 32 + quad * 8];
#pragma unroll
            for (int ht = 0; ht < 4; ++ht) {
                short8 bf = *(const short8*)&Vs[(ht * 16 + l15) * LD + kk * 32 + quad * 8];
                ov[ht] = __builtin_amdgcn_mfma_f32_16x16x32_bf16(a, bf, ov[ht], 0, 0, 0);
            }
        }
    }

    // write partials (unnormalized)
    float* Ob = Opart + ((size_t)((b * 64 + qt) * NCH + c)) * 4096;
#pragma unroll
    for (int ht = 0; ht < 4; ++ht)
#pragma unroll
        for (int r = 0; r < 4; ++r)
            Ob[(size_t)(wave * 16 + quad * 4 + r) * HH + ht * 16 + l15] = ov[ht][r];
    if (quad == 0) {
        size_t mi = (size_t)((b * 64 + qt) * NCH + c) * 64 + wave * 16 + l15;
        Mpart[mi] = m_run;
        Lpart[mi] = l_run;
    }
}

// ---------------------------------------------------------------------------
// Kernel 3: combine partials across chunks, normalize, write fp32 out.
// Grid (64, 4) x 256 thr; thread owns 16 output floats of one row.
// ---------------------------------------------------------------------------
__global__ __launch_bounds__(256) void combine(
    const float* __restrict__ Opart,
    const float* __restrict__ Mpart,
    const float* __restrict__ Lpart,
    float* __restrict__ out)
{
    const int qt = blockIdx.x;
    const int b  = blockIdx.y;
    const int nc = (qt >> 4) + 1;
    const int t  = threadIdx.x;
    const int row = t >> 2;
    const int seg = t & 3;

    const size_t base = (size_t)(b * 64 + qt) * NCH;

    float m_c[NCH], M = -1e30f;
    for (int c = 0; c < nc; ++c) {
        m_c[c] = Mpart[(base + c) * 64 + row];
        M = fmaxf(M, m_c[c]);
    }
    float L = 0.f, w_c[NCH];
    for (int c = 0; c < nc; ++c) {
        w_c[c] = __expf(m_c[c] - M);
        L += w_c[c] * Lpart[(base + c) * 64 + row];
    }
    float invL = 1.0f / L;

    f32x4 o[4];
#pragma unroll
    for (int i = 0; i < 4; ++i) o[i] = (f32x4){0.f, 0.f, 0.f, 0.f};
    for (int c = 0; c < nc; ++c) {
        const float* Ob = Opart + (base + c) * 4096 + (size_t)row * HH + seg * 16;
#pragma unroll
        for (int i = 0; i < 4; ++i) {
            f32x4 v = *(const f32x4*)(Ob + i * 4);
            o[i] += v * w_c[c];
        }
    }
    float* op = out + ((size_t)b * TT + qt * 64 + row) * HH + seg * 16;
#pragma unroll
    for (int i = 0; i < 4; ++i)
        *(f32x4*)(op + i * 4) = o[i] * invL;
}

extern "C" void kernel_launch(void* const* d_in, const int* in_sizes, int n_in,
                              void* d_out, int out_size, void* d_ws, size_t ws_size,
                              hipStream_t stream) {
    const float* x  = (const float*)d_in[0];
    const float* Wq = (const float*)d_in[1];
    const float* Wk = (const float*)d_in[2];
    const float* Wv = (const float*)d_in[3];
    float* out = (float*)d_out;

    unsigned short* qkv = (unsigned short*)d_ws;                 // 6.29 MB bf16
    float* Opart = (float*)((char*)d_ws + BF_TOTAL * 2);         // 16.78 MB
    float* Mpart = Opart + (size_t)BB * 64 * NCH * 4096;         // 0.26 MB
    float* Lpart = Mpart + (size_t)BB * 64 * NCH * 64;           // 0.26 MB

    unsigned short* Wt = (unsigned short*)d_out;  // 384 KB pre-scratch; combine
                                                  // fully overwrites d_out later

    transpose_w<<<dim3(16, 3), 256, 0, stream>>>(Wq, Wk, Wv, Wt);
    qkv_proj<<<dim3(MTOT / 32), 256, 0, stream>>>(x, Wt, qkv);
    flash_attn<<<dim3(64, BB, NCH), 256, 0, stream>>>(qkv, Opart, Mpart, Lpart);
    combine<<<dim3(64, BB), 256, 0, stream>>>(Opart, Mpart, Lpart, out);
}